// Round 1
// baseline (451.962 us; speedup 1.0000x reference)
//
#include <hip/hip_runtime.h>

#define ROWS 16384
#define COLS 4096
#define KSEL 512
#define THREADS 256
// 4096 / 256 = 16 elements per thread = 4 x float4

__device__ __forceinline__ unsigned map_f(float f) {
    unsigned u = __float_as_uint(f);
    // order-preserving map: negative -> ~u, positive -> u | signbit
    return (u & 0x80000000u) ? ~u : (u | 0x80000000u);
}

__device__ __forceinline__ float unmap_f(unsigned u) {
    unsigned b = (u & 0x80000000u) ? (u & 0x7FFFFFFFu) : ~u;
    return __uint_as_float(b);
}

__global__ __launch_bounds__(THREADS) void kwta_kernel(const float* __restrict__ in,
                                                       float* __restrict__ out) {
    __shared__ unsigned hist[256];
    __shared__ unsigned scan[256];
    __shared__ unsigned sh_prefix;
    __shared__ unsigned sh_k;

    const int row = blockIdx.x;
    const int t = threadIdx.x;
    const float4* __restrict__ inrow  = (const float4*)(in  + (size_t)row * COLS);
    float4* __restrict__ outrow       = (float4*)(out + (size_t)row * COLS);

    // Load 16 floats per thread, coalesced float4s.
    float4 f[4];
#pragma unroll
    for (int i = 0; i < 4; i++) f[i] = inrow[t + i * THREADS];

    unsigned v[16];
#pragma unroll
    for (int i = 0; i < 4; i++) {
        v[4 * i + 0] = map_f(f[i].x);
        v[4 * i + 1] = map_f(f[i].y);
        v[4 * i + 2] = map_f(f[i].z);
        v[4 * i + 3] = map_f(f[i].w);
    }

    unsigned prefix = 0;   // selected high bits so far (mapped space)
    unsigned kk = KSEL;    // k-th largest among remaining candidates

#pragma unroll
    for (int pass = 0; pass < 4; pass++) {
        const int shift = 24 - 8 * pass;

        hist[t] = 0;
        __syncthreads();

        // histogram of current byte over candidates (high bits == prefix)
        const unsigned pmask = (pass == 0) ? 0u : (0xFFFFFFFFu << (shift + 8));
#pragma unroll
        for (int i = 0; i < 16; i++) {
            if (pass == 0 || ((v[i] ^ prefix) & pmask) == 0u) {
                atomicAdd(&hist[(v[i] >> shift) & 255u], 1u);
            }
        }
        __syncthreads();

        // reverse inclusive scan: scan[d] = sum_{j >= d} hist[j]
        scan[t] = hist[t];
        __syncthreads();
#pragma unroll
        for (int off = 1; off < 256; off <<= 1) {
            unsigned add = (t + off < 256) ? scan[t + off] : 0u;
            __syncthreads();
            scan[t] += add;
            __syncthreads();
        }
        const unsigned S       = scan[t];                      // count with digit >= t
        const unsigned S_above = (t == 255) ? 0u : scan[t + 1]; // count with digit > t

        // unique t with S >= kk > S_above holds the k-th largest digit
        if (S >= kk && S_above < kk) {
            sh_prefix = prefix | ((unsigned)t << shift);
            sh_k      = kk - S_above;
        }
        __syncthreads();
        prefix = sh_prefix;
        kk     = sh_k;
        __syncthreads();
    }

    // prefix is the exact mapped bit pattern of the K-th largest value
    const float thresh = unmap_f(prefix);

#pragma unroll
    for (int i = 0; i < 4; i++) {
        float4 o;
        o.x = (f[i].x >= thresh) ? f[i].x : 0.0f;
        o.y = (f[i].y >= thresh) ? f[i].y : 0.0f;
        o.z = (f[i].z >= thresh) ? f[i].z : 0.0f;
        o.w = (f[i].w >= thresh) ? f[i].w : 0.0f;
        outrow[t + i * THREADS] = o;
    }
}

extern "C" void kernel_launch(void* const* d_in, const int* in_sizes, int n_in,
                              void* d_out, int out_size, void* d_ws, size_t ws_size,
                              hipStream_t stream) {
    const float* s = (const float*)d_in[0];
    float* out = (float*)d_out;
    kwta_kernel<<<ROWS, THREADS, 0, stream>>>(s, out);
}

// Round 2
// 441.566 us; speedup vs baseline: 1.0235x; 1.0235x over previous
//
#include <hip/hip_runtime.h>

#define ROWS 16384
#define COLS 4096
#define KSEL 512
#define WAVES_PER_BLOCK 4
#define THREADS (WAVES_PER_BLOCK * 64)
#define NCOPY 4
#define HSTRIDE 260  // words/copy: 260%32==4 -> bank-skewed copies; 1040B -> 16B aligned

// order-preserving float->uint map: compare as unsigned == compare as float
__device__ __forceinline__ unsigned map_f(float f) {
    unsigned u = __float_as_uint(f);
    return u ^ (0x80000000u | (unsigned)((int)u >> 31));
}
__device__ __forceinline__ float unmap_f(unsigned m) {
    return __uint_as_float(m ^ (0x80000000u | ~(unsigned)((int)m >> 31)));
}

__global__ __launch_bounds__(THREADS, 4) void kwta_kernel(const float* __restrict__ in,
                                                          float* __restrict__ out) {
    // one wave per row; per-wave private histogram, 4 bank-skewed copies
    __shared__ __align__(16) unsigned histmem[WAVES_PER_BLOCK][NCOPY * HSTRIDE];

    const int lane = threadIdx.x & 63;
    const int wave = threadIdx.x >> 6;
    const int row  = blockIdx.x * WAVES_PER_BLOCK + wave;
    unsigned* h = histmem[wave];
    const int copy = (lane & 3) * HSTRIDE;

    const float4* __restrict__ inrow  = (const float4*)(in  + (size_t)row * COLS);
    float4*       __restrict__ outrow = (float4*)(out + (size_t)row * COLS);

    // 64 elements per lane, coalesced float4 loads, mapped in place
    unsigned v[64];
#pragma unroll
    for (int i = 0; i < 16; i++) {
        float4 f = inrow[lane + 64 * i];
        v[4 * i + 0] = map_f(f.x);
        v[4 * i + 1] = map_f(f.y);
        v[4 * i + 2] = map_f(f.z);
        v[4 * i + 3] = map_f(f.w);
    }

    unsigned prefix = 0;  // selected high bits (mapped space)
    unsigned kk = KSEL;

#pragma unroll
    for (int pass = 0; pass < 4; pass++) {
        const int shift = 24 - 8 * pass;

        // zero all copies: 260 uint4s across 64 lanes
        uint4 z = make_uint4(0u, 0u, 0u, 0u);
#pragma unroll
        for (int i = 0; i < 5; i++) {
            int w4 = lane + 64 * i;
            if (w4 < (NCOPY * HSTRIDE) / 4) ((uint4*)h)[w4] = z;
        }

        // histogram of current byte over candidates (wave-private: no barrier,
        // same-wave LDS ops execute in issue order; compiler inserts lgkmcnt)
        if (pass == 0) {
#pragma unroll
            for (int i = 0; i < 64; i++)
                atomicAdd(&h[copy + (v[i] >> 24)], 1u);
        } else {
            const int hs = shift + 8;
#pragma unroll
            for (int i = 0; i < 64; i++) {
                if (((v[i] ^ prefix) >> hs) == 0u)
                    atomicAdd(&h[copy + ((v[i] >> shift) & 255u)], 1u);
            }
        }

        // lane owns bins [4*lane, 4*lane+3]; sum the 4 copies
        uint4 c0 = ((const uint4*)(h + 0 * HSTRIDE))[lane];
        uint4 c1 = ((const uint4*)(h + 1 * HSTRIDE))[lane];
        uint4 c2 = ((const uint4*)(h + 2 * HSTRIDE))[lane];
        uint4 c3 = ((const uint4*)(h + 3 * HSTRIDE))[lane];
        unsigned n0 = c0.x + c1.x + c2.x + c3.x;
        unsigned n1 = c0.y + c1.y + c2.y + c3.y;
        unsigned n2 = c0.z + c1.z + c2.z + c3.z;
        unsigned n3 = c0.w + c1.w + c2.w + c3.w;

        unsigned ls3 = n3, ls2 = n3 + n2, ls1 = ls2 + n1, tot = ls1 + n0;

        // suffix-inclusive scan of per-lane totals across the wave
        unsigned S = tot;
#pragma unroll
        for (int off = 1; off < 64; off <<= 1) {
            unsigned o = __shfl(S, lane + off);
            S += (lane + off < 64) ? o : 0u;
        }
        const unsigned R = S - tot;  // count with digit >= 4*(lane+1)

        const unsigned S3 = R + ls3, S2 = R + ls2, S1 = R + ls1, S0 = R + tot;
        unsigned dig = 0, nk = 0;
        bool found = false;
        if (S3 >= kk && R  < kk) { dig = 4 * lane + 3; nk = kk - R;  found = true; }
        if (S2 >= kk && S3 < kk) { dig = 4 * lane + 2; nk = kk - S3; found = true; }
        if (S1 >= kk && S2 < kk) { dig = 4 * lane + 1; nk = kk - S2; found = true; }
        if (S0 >= kk && S1 < kk) { dig = 4 * lane + 0; nk = kk - S1; found = true; }

        unsigned long long m = __ballot(found);
        int src = (int)__ffsll((unsigned long long)m) - 1;
        dig = __shfl(dig, src);
        nk  = __shfl(nk, src);

        prefix |= dig << shift;
        kk = nk;
    }

    // prefix == mapped bit pattern of the exact K-th largest; compare in mapped space
#pragma unroll
    for (int i = 0; i < 16; i++) {
        float4 o;
        o.x = (v[4 * i + 0] >= prefix) ? unmap_f(v[4 * i + 0]) : 0.0f;
        o.y = (v[4 * i + 1] >= prefix) ? unmap_f(v[4 * i + 1]) : 0.0f;
        o.z = (v[4 * i + 2] >= prefix) ? unmap_f(v[4 * i + 2]) : 0.0f;
        o.w = (v[4 * i + 3] >= prefix) ? unmap_f(v[4 * i + 3]) : 0.0f;
        outrow[lane + 64 * i] = o;
    }
}

extern "C" void kernel_launch(void* const* d_in, const int* in_sizes, int n_in,
                              void* d_out, int out_size, void* d_ws, size_t ws_size,
                              hipStream_t stream) {
    const float* s = (const float*)d_in[0];
    float* out = (float*)d_out;
    kwta_kernel<<<ROWS / WAVES_PER_BLOCK, THREADS, 0, stream>>>(s, out);
}

// Round 3
// 428.960 us; speedup vs baseline: 1.0536x; 1.0294x over previous
//
#include <hip/hip_runtime.h>

#define ROWS 16384
#define COLS 4096
#define KSEL 512
#define THREADS 256
#define NCOPY0 8       // pass-0 histogram copies (hot bins from normal data)
#define HSTRIDE 260    // words per copy: bank-skewed (260%32==4), 16B-aligned
// LDS: (NCOPY0 + 3) * HSTRIDE * 4 = 11440 B -> 8 blocks/CU uses 89 KB of 160 KB

// order-preserving float->uint map: compare as unsigned == compare as float
__device__ __forceinline__ unsigned map_f(float f) {
    unsigned u = __float_as_uint(f);
    return u ^ (0x80000000u | (unsigned)((int)u >> 31));
}
__device__ __forceinline__ float unmap_f(unsigned m) {
    return __uint_as_float(m ^ (0x80000000u | ~(unsigned)((int)m >> 31)));
}

// wave-redundant digit select: lane owns bins [4*lane .. 4*lane+3] with counts
// n0..n3; suffix-scan across the wave locates the digit containing rank kk.
__device__ __forceinline__ void select_digit(unsigned n0, unsigned n1, unsigned n2,
                                             unsigned n3, int lane, int shift,
                                             unsigned& prefix, unsigned& kk) {
    unsigned ls3 = n3, ls2 = n3 + n2, ls1 = ls2 + n1, tot = ls1 + n0;
    unsigned S = tot;
#pragma unroll
    for (int off = 1; off < 64; off <<= 1) {
        unsigned o = __shfl(S, lane + off);
        S += (lane + off < 64) ? o : 0u;
    }
    const unsigned R = S - tot;  // count with digit >= 4*(lane+1)
    const unsigned S3 = R + ls3, S2 = R + ls2, S1 = R + ls1, S0 = R + tot;
    unsigned dig = 0, nk = 0;
    bool found = false;
    if (S3 >= kk && R  < kk) { dig = 4 * lane + 3; nk = kk - R;  found = true; }
    if (S2 >= kk && S3 < kk) { dig = 4 * lane + 2; nk = kk - S3; found = true; }
    if (S1 >= kk && S2 < kk) { dig = 4 * lane + 1; nk = kk - S2; found = true; }
    if (S0 >= kk && S1 < kk) { dig = 4 * lane + 0; nk = kk - S1; found = true; }
    unsigned long long m = __ballot(found);
    int src = (int)__ffsll(m) - 1;
    prefix |= (unsigned)__shfl(dig, src) << shift;
    kk = (unsigned)__shfl(nk, src);
}

__global__ __launch_bounds__(THREADS, 8) void kwta_kernel(const float* __restrict__ in,
                                                          float* __restrict__ out) {
    __shared__ __align__(16) unsigned hist[(NCOPY0 + 3) * HSTRIDE];

    const int tid  = threadIdx.x;
    const int lane = tid & 63;
    const int row  = blockIdx.x;

    const float4* __restrict__ inrow  = (const float4*)(in  + (size_t)row * COLS);
    float4*       __restrict__ outrow = (float4*)(out + (size_t)row * COLS);

    // 16 elements per thread, coalesced float4 loads, mapped in place
    unsigned v[16];
#pragma unroll
    for (int i = 0; i < 4; i++) {
        float4 f = inrow[tid + THREADS * i];
        v[4 * i + 0] = map_f(f.x);
        v[4 * i + 1] = map_f(f.y);
        v[4 * i + 2] = map_f(f.z);
        v[4 * i + 3] = map_f(f.w);
    }

    // zero all histogram buffers once (single hazard barrier for the whole kernel)
    {
        const uint4 z = make_uint4(0u, 0u, 0u, 0u);
#pragma unroll
        for (int i = 0; i < 3; i++) {
            int w4 = tid + THREADS * i;
            if (w4 < (NCOPY0 + 3) * HSTRIDE / 4) ((uint4*)hist)[w4] = z;
        }
    }
    __syncthreads();

    unsigned prefix = 0;  // selected high bits (mapped space)
    unsigned kk = KSEL;

    // ---- pass 0: top byte, 8-copy histogram (contention-spread) ----
    {
        unsigned* h0 = hist + (tid & (NCOPY0 - 1)) * HSTRIDE;
#pragma unroll
        for (int i = 0; i < 16; i++) atomicAdd(&h0[v[i] >> 24], 1u);
        __syncthreads();
        unsigned n0 = 0, n1 = 0, n2 = 0, n3 = 0;
#pragma unroll
        for (int c = 0; c < NCOPY0; c++) {
            uint4 t = ((const uint4*)(hist + c * HSTRIDE))[lane];
            n0 += t.x; n1 += t.y; n2 += t.z; n3 += t.w;
        }
        select_digit(n0, n1, n2, n3, lane, 24, prefix, kk);
    }

    // ---- passes 1..3: private single-copy buffers (uniform digits, no contention;
    // disjoint LDS regions per pass -> atomics of pass p never race reads of pass p-1)
#pragma unroll
    for (int pass = 1; pass < 4; pass++) {
        const int shift = 24 - 8 * pass;
        const int hs = shift + 8;
        unsigned* hp = hist + (NCOPY0 + pass - 1) * HSTRIDE;
#pragma unroll
        for (int i = 0; i < 16; i++) {
            if (((v[i] ^ prefix) >> hs) == 0u)
                atomicAdd(&hp[(v[i] >> shift) & 255u], 1u);
        }
        __syncthreads();
        uint4 t = ((const uint4*)hp)[lane];
        select_digit(t.x, t.y, t.z, t.w, lane, shift, prefix, kk);
    }

    // prefix == mapped bit pattern of the exact K-th largest; compare in mapped space
#pragma unroll
    for (int i = 0; i < 4; i++) {
        float4 o;
        o.x = (v[4 * i + 0] >= prefix) ? unmap_f(v[4 * i + 0]) : 0.0f;
        o.y = (v[4 * i + 1] >= prefix) ? unmap_f(v[4 * i + 1]) : 0.0f;
        o.z = (v[4 * i + 2] >= prefix) ? unmap_f(v[4 * i + 2]) : 0.0f;
        o.w = (v[4 * i + 3] >= prefix) ? unmap_f(v[4 * i + 3]) : 0.0f;
        outrow[tid + THREADS * i] = o;
    }
}

extern "C" void kernel_launch(void* const* d_in, const int* in_sizes, int n_in,
                              void* d_out, int out_size, void* d_ws, size_t ws_size,
                              hipStream_t stream) {
    const float* s = (const float*)d_in[0];
    float* out = (float*)d_out;
    kwta_kernel<<<ROWS, THREADS, 0, stream>>>(s, out);
}